// Round 3
// baseline (1467.854 us; speedup 1.0000x reference)
//
#include <hip/hip_runtime.h>

// Transformer block: B=64, T=320, E=1024, H=16, HS=64
// Round 2: bf16 MFMA GEMMs (QKV fused, Wo, W1, W2) + fp32 flash attention.
// Weights transpose-cast to bf16 [N][K] once per launch. LDS 16B-slot XOR
// swizzle on GEMM tiles. Attention reads bf16 q/k/v, computes fp32.

#define B_ 64
#define T_ 320
#define E_ 1024
#define H_ 16
#define HS_ 64
#define NTOK (B_ * T_)   // 20480

typedef __attribute__((ext_vector_type(8))) __bf16 bf16x8;
typedef __attribute__((ext_vector_type(4))) float f32x4;

__device__ __forceinline__ unsigned short f2bf(float f) {
    unsigned u = __builtin_bit_cast(unsigned, f);
    u += 0x7fffu + ((u >> 16) & 1u);          // round-to-nearest-even
    return (unsigned short)(u >> 16);
}
__device__ __forceinline__ float bf2f(unsigned short b) {
    return __builtin_bit_cast(float, (unsigned)b << 16);
}

// ------------------------------------------------------------ LayerNorm -> bf16
__global__ __launch_bounds__(256) void ln_kernel(const float* __restrict__ x,
                                                 const float* __restrict__ w,
                                                 const float* __restrict__ b,
                                                 unsigned short* __restrict__ y) {
    int row = blockIdx.x;
    int t = threadIdx.x;
    const float4* xr = (const float4*)(x + (size_t)row * E_);
    float4 v = xr[t];
    float s = v.x + v.y + v.z + v.w;
    float s2 = v.x * v.x + v.y * v.y + v.z * v.z + v.w * v.w;
#pragma unroll
    for (int o = 1; o < 64; o <<= 1) {
        s += __shfl_xor(s, o);
        s2 += __shfl_xor(s2, o);
    }
    __shared__ float rs[4], rs2[4];
    int wv = t >> 6;
    if ((t & 63) == 0) { rs[wv] = s; rs2[wv] = s2; }
    __syncthreads();
    s = rs[0] + rs[1] + rs[2] + rs[3];
    s2 = rs2[0] + rs2[1] + rs2[2] + rs2[3];
    float mu = s * (1.0f / E_);
    float var = s2 * (1.0f / E_) - mu * mu;
    float inv = rsqrtf(var + 1e-5f);
    float4 w4 = ((const float4*)w)[t];
    float4 b4 = ((const float4*)b)[t];
    ushort4 o4;
    o4.x = f2bf((v.x - mu) * inv * w4.x + b4.x);
    o4.y = f2bf((v.y - mu) * inv * w4.y + b4.y);
    o4.z = f2bf((v.z - mu) * inv * w4.z + b4.z);
    o4.w = f2bf((v.w - mu) * inv * w4.w + b4.w);
    *(ushort4*)(y + (size_t)row * E_ + 4 * t) = o4;
}

// ------------------------------------------------- transpose-cast fp32->bf16
// src fp32 [K][N] (+z*sStride), dst bf16 [N][K] (+z*dStride). 64x64 tiles.
__global__ __launch_bounds__(256) void tcast_kernel(const float* __restrict__ src,
                                                    unsigned short* __restrict__ dst,
                                                    int K, int N, long sStride, long dStride) {
    src += (size_t)blockIdx.z * sStride;
    dst += (size_t)blockIdx.z * dStride;
    __shared__ float tile[64][65];
    int k0 = blockIdx.y * 64, n0 = blockIdx.x * 64;
    int tx = threadIdx.x & 63, ty = threadIdx.x >> 6;
#pragma unroll
    for (int r = ty; r < 64; r += 4)
        tile[r][tx] = src[(size_t)(k0 + r) * N + n0 + tx];
    __syncthreads();
#pragma unroll
    for (int r = ty; r < 64; r += 4)
        dst[(size_t)(n0 + r) * K + k0 + tx] = f2bf(tile[tx][r]);
}

// ------------------------------------------------------------- MFMA GEMM
// C[M,N] = epilogue( A[M,K]bf16 @ Bt[N,K]bf16^T ). 128x128 tile, BK=32,
// 4 waves (2x2), each wave 64x64 = 4x4 frags of 16x16x32.
// LDS tiles [128 rows][4 slots of 16B], slot ^= (row>>1)&3 (2-way = free).
template <bool BF16OUT, bool BIAS, bool RELU, bool RESID>
__global__ __launch_bounds__(256)
void gemm_mfma(const unsigned short* __restrict__ A,   // [M][K] bf16
               const unsigned short* __restrict__ Bt,  // [N][K] bf16
               const float* __restrict__ bias,         // [N] fp32
               const float* __restrict__ resid,        // [M][N] fp32
               void* __restrict__ Cout, int K, int N) {
    __shared__ uint4 A4[128 * 4];
    __shared__ uint4 B4[128 * 4];
    const int tid = threadIdx.x;
    const int lane = tid & 63;
    const int wave = tid >> 6;
    const int wr = wave >> 1, wc = wave & 1;
    const int m0 = blockIdx.y * 128;
    const int n0 = blockIdx.x * 128;
    const int r16 = lane & 15;          // row/col within a 16-frag
    const int s = lane >> 4;            // k-slot (8 bf16 = 16B each)
    const int sw = s ^ ((r16 >> 1) & 3);

    // staging: 512 16B-chunks; thread t takes chunks t and t+256
    const int ar0 = tid >> 2, as0 = tid & 3;
    const int asw = as0 ^ ((ar0 >> 1) & 3);
    const unsigned short* Ag = A + (size_t)(m0 + ar0) * K + as0 * 8;
    const unsigned short* Bg = Bt + (size_t)(n0 + ar0) * K + as0 * 8;
    const size_t rowSkip = (size_t)64 * K;

    f32x4 acc[4][4];
#pragma unroll
    for (int i = 0; i < 4; i++)
#pragma unroll
        for (int j = 0; j < 4; j++) acc[i][j] = (f32x4){0.f, 0.f, 0.f, 0.f};

    const bf16x8* Ab = (const bf16x8*)A4;
    const bf16x8* Bb = (const bf16x8*)B4;

    for (int k0 = 0; k0 < K; k0 += 32) {
        uint4 a0 = *(const uint4*)(Ag + k0);
        uint4 a1 = *(const uint4*)(Ag + rowSkip + k0);
        uint4 b0 = *(const uint4*)(Bg + k0);
        uint4 b1 = *(const uint4*)(Bg + rowSkip + k0);
        __syncthreads();                 // previous-iter readers done
        A4[(ar0 << 2) + asw] = a0;
        A4[((ar0 + 64) << 2) + asw] = a1;
        B4[(ar0 << 2) + asw] = b0;
        B4[((ar0 + 64) << 2) + asw] = b1;
        __syncthreads();
        bf16x8 af[4], bf[4];
#pragma unroll
        for (int i = 0; i < 4; i++) {
            af[i] = Ab[(((wr << 6) + (i << 4) + r16) << 2) + sw];
            bf[i] = Bb[(((wc << 6) + (i << 4) + r16) << 2) + sw];
        }
#pragma unroll
        for (int i = 0; i < 4; i++)
#pragma unroll
            for (int j = 0; j < 4; j++)
                acc[i][j] = __builtin_amdgcn_mfma_f32_16x16x32_bf16(af[i], bf[j], acc[i][j], 0, 0, 0);
    }

    // epilogue: D row = s*4 + r (within frag), col = r16
    const int crow0 = m0 + wr * 64;
    const int ccol0 = n0 + wc * 64;
#pragma unroll
    for (int j = 0; j < 4; j++) {
        int gcol = ccol0 + j * 16 + r16;
        float bv = BIAS ? bias[gcol] : 0.f;
#pragma unroll
        for (int i = 0; i < 4; i++) {
            int growb = crow0 + i * 16 + s * 4;
#pragma unroll
            for (int r = 0; r < 4; r++) {
                float vo = acc[i][j][r] + bv;
                if (RELU) vo = fmaxf(vo, 0.f);
                int grow = growb + r;
                if (RESID) vo += resid[(size_t)grow * N + gcol];
                if (BF16OUT)
                    ((unsigned short*)Cout)[(size_t)grow * N + gcol] = f2bf(vo);
                else
                    ((float*)Cout)[(size_t)grow * N + gcol] = vo;
            }
        }
    }
}

// ------------------------------------------------------------- Flash attn
// qkv bf16 [NTOK][3072]: cols [0,1024)=q, [1024,2048)=k, [2048,3072)=v,
// each section laid out (B,T,H,HS). fp32 math, bf16 out (B,T,E).
__global__ __launch_bounds__(256) void attn_kernel(const unsigned short* __restrict__ qkv,
                                                   unsigned short* __restrict__ attn) {
    int it = blockIdx.x;    // q tile
    int bh = blockIdx.y;    // b*H + h
    int b = bh >> 4, head = bh & 15;
    __shared__ float Qs[64][65], KPs[64][65], Vs[64][65];
    int tid = threadIdx.x;
    int tx = tid & 15, ty = tid >> 4;
    const size_t rstr = 3 * E_;
    const unsigned short* qb = qkv + (size_t)(b * T_ + it * 64) * rstr + head * HS_;
    const unsigned short* kb = qkv + (size_t)(b * T_) * rstr + E_ + head * HS_;
    const unsigned short* vb = qkv + (size_t)(b * T_) * rstr + 2 * E_ + head * HS_;
    int r = tid >> 4, c4 = (tid & 15) << 2;
#pragma unroll
    for (int rr = 0; rr < 4; rr++) {
        int row = rr * 16 + r;
        ushort4 t4 = *(const ushort4*)(qb + (size_t)row * rstr + c4);
        Qs[row][c4 + 0] = bf2f(t4.x) * 0.03125f;   // * E^-0.5
        Qs[row][c4 + 1] = bf2f(t4.y) * 0.03125f;
        Qs[row][c4 + 2] = bf2f(t4.z) * 0.03125f;
        Qs[row][c4 + 3] = bf2f(t4.w) * 0.03125f;
    }
    float O[4][4] = {};
    float m[4] = {-1e30f, -1e30f, -1e30f, -1e30f};
    float l[4] = {};
    int r0 = ty << 2, c0 = tx << 2;
    for (int j = 0; j <= it; j++) {
        __syncthreads();
#pragma unroll
        for (int rr = 0; rr < 4; rr++) {
            int row = rr * 16 + r;
            ushort4 k4 = *(const ushort4*)(kb + (size_t)(j * 64 + row) * rstr + c4);
            ushort4 v4 = *(const ushort4*)(vb + (size_t)(j * 64 + row) * rstr + c4);
            KPs[row][c4 + 0] = bf2f(k4.x); KPs[row][c4 + 1] = bf2f(k4.y);
            KPs[row][c4 + 2] = bf2f(k4.z); KPs[row][c4 + 3] = bf2f(k4.w);
            Vs[row][c4 + 0] = bf2f(v4.x); Vs[row][c4 + 1] = bf2f(v4.y);
            Vs[row][c4 + 2] = bf2f(v4.z); Vs[row][c4 + 3] = bf2f(v4.w);
        }
        __syncthreads();
        float sA[4][4] = {};
#pragma unroll
        for (int d = 0; d < 64; d++) {
            float qa[4], kv[4];
#pragma unroll
            for (int a = 0; a < 4; a++) qa[a] = Qs[r0 + a][d];
#pragma unroll
            for (int bb = 0; bb < 4; bb++) kv[bb] = KPs[c0 + bb][d];
#pragma unroll
            for (int a = 0; a < 4; a++)
#pragma unroll
                for (int bb = 0; bb < 4; bb++) sA[a][bb] += qa[a] * kv[bb];
        }
        if (j == it) {
#pragma unroll
            for (int a = 0; a < 4; a++)
#pragma unroll
                for (int bb = 0; bb < 4; bb++)
                    if (c0 + bb > r0 + a) sA[a][bb] = -1e30f;
        }
        float p[4][4];
#pragma unroll
        for (int a = 0; a < 4; a++) {
            float mx = fmaxf(fmaxf(sA[a][0], sA[a][1]), fmaxf(sA[a][2], sA[a][3]));
#pragma unroll
            for (int o = 1; o < 16; o <<= 1) mx = fmaxf(mx, __shfl_xor(mx, o));
            float mn = fmaxf(m[a], mx);
            float al = __expf(m[a] - mn);
            m[a] = mn;
            float su = 0.f;
#pragma unroll
            for (int bb = 0; bb < 4; bb++) {
                float pe = __expf(sA[a][bb] - mn);
                p[a][bb] = pe;
                su += pe;
            }
#pragma unroll
            for (int o = 1; o < 16; o <<= 1) su += __shfl_xor(su, o);
            l[a] = l[a] * al + su;
#pragma unroll
            for (int bb = 0; bb < 4; bb++) O[a][bb] *= al;
        }
        __syncthreads();
#pragma unroll
        for (int a = 0; a < 4; a++)
#pragma unroll
            for (int bb = 0; bb < 4; bb++) KPs[r0 + a][c0 + bb] = p[a][bb];
        __syncthreads();
#pragma unroll 8
        for (int sidx = 0; sidx < 64; sidx++) {
            float pa[4], vv[4];
#pragma unroll
            for (int a = 0; a < 4; a++) pa[a] = KPs[r0 + a][sidx];
#pragma unroll
            for (int bb = 0; bb < 4; bb++) vv[bb] = Vs[sidx][c0 + bb];
#pragma unroll
            for (int a = 0; a < 4; a++)
#pragma unroll
                for (int bb = 0; bb < 4; bb++) O[a][bb] += pa[a] * vv[bb];
        }
    }
#pragma unroll
    for (int a = 0; a < 4; a++) {
        float inv = 1.0f / l[a];
        ushort4 o4;
        o4.x = f2bf(O[a][0] * inv); o4.y = f2bf(O[a][1] * inv);
        o4.z = f2bf(O[a][2] * inv); o4.w = f2bf(O[a][3] * inv);
        *(ushort4*)(attn + (size_t)(b * T_ + it * 64 + r0 + a) * E_ + head * HS_ + c0) = o4;
    }
}

// ---------------------------------------------------------------- launch
extern "C" void kernel_launch(void* const* d_in, const int* in_sizes, int n_in,
                              void* d_out, int out_size, void* d_ws, size_t ws_size,
                              hipStream_t stream) {
    const float* x    = (const float*)d_in[0];
    const float* Wq   = (const float*)d_in[1];
    const float* Wk   = (const float*)d_in[2];
    const float* Wv   = (const float*)d_in[3];
    const float* Wo   = (const float*)d_in[4];
    const float* bo   = (const float*)d_in[5];
    const float* W1   = (const float*)d_in[6];
    const float* b1   = (const float*)d_in[7];
    const float* W2   = (const float*)d_in[8];
    const float* b2   = (const float*)d_in[9];
    const float* ln1w = (const float*)d_in[10];
    const float* ln1b = (const float*)d_in[11];
    const float* ln2w = (const float*)d_in[12];
    const float* ln2b = (const float*)d_in[13];
    float* out = (float*)d_out;

    // ws layout (bf16 = ushort elements)
    unsigned short* ws = (unsigned short*)d_ws;
    unsigned short* qkvWt = ws;                        //  [3072][1024]  6.3 MB
    unsigned short* WoT   = qkvWt + 3072 * 1024;       //  [1024][1024]  2.1 MB
    unsigned short* W1T   = WoT + 1024 * 1024;         //  [4096][1024]  8.4 MB
    unsigned short* W2T   = W1T + 4096 * 1024;         //  [1024][4096]  8.4 MB
    unsigned short* hbuf  = W2T + 1024 * 4096;         //  [20480][1024] 41.9 MB
    unsigned short* qkv   = hbuf + (size_t)NTOK * E_;  //  [20480][3072] 125.8 MB
    unsigned short* abuf  = qkv + (size_t)NTOK * 3 * E_; // [20480][1024] 41.9 MB
    unsigned short* inter = qkv;                       //  [20480][4096] overlays qkv+abuf

    // --- weight transpose-casts (per launch; ~13M elems total) ---
    tcast_kernel<<<dim3(1, 16, 16), 256, 0, stream>>>(Wq, qkvWt, E_, HS_,
                                                      (long)E_ * HS_, (long)HS_ * E_);
    tcast_kernel<<<dim3(1, 16, 16), 256, 0, stream>>>(Wk, qkvWt + 1024 * 1024, E_, HS_,
                                                      (long)E_ * HS_, (long)HS_ * E_);
    tcast_kernel<<<dim3(1, 16, 16), 256, 0, stream>>>(Wv, qkvWt + 2048 * 1024, E_, HS_,
                                                      (long)E_ * HS_, (long)HS_ * E_);
    tcast_kernel<<<dim3(16, 16, 1), 256, 0, stream>>>(Wo, WoT, E_, E_, 0, 0);
    tcast_kernel<<<dim3(64, 16, 1), 256, 0, stream>>>(W1, W1T, E_, 4 * E_, 0, 0);
    tcast_kernel<<<dim3(16, 64, 1), 256, 0, stream>>>(W2, W2T, 4 * E_, E_, 0, 0);

    // 1) h = LN1(x) -> bf16
    ln_kernel<<<NTOK, 256, 0, stream>>>(x, ln1w, ln1b, hbuf);
    // 2) qkv = h @ [Wq|Wk|Wv]  (M=20480, N=3072, K=1024) -> bf16
    gemm_mfma<true, false, false, false><<<dim3(24, 160), 256, 0, stream>>>(
        hbuf, qkvWt, nullptr, nullptr, qkv, 1024, 3072);
    // 3) attention -> bf16 (B,T,E)
    attn_kernel<<<dim3(T_ / 64, B_ * H_), 256, 0, stream>>>(qkv, abuf);
    // 4) x1 = x + attn @ Wo + bo -> fp32 d_out
    gemm_mfma<false, true, false, true><<<dim3(8, 160), 256, 0, stream>>>(
        abuf, WoT, bo, x, out, 1024, 1024);
    // 5) h2 = LN2(x1) -> bf16
    ln_kernel<<<NTOK, 256, 0, stream>>>(out, ln2w, ln2b, hbuf);
    // 6) inter = relu(h2 @ W1 + b1) -> bf16
    gemm_mfma<true, true, true, false><<<dim3(32, 160), 256, 0, stream>>>(
        hbuf, W1T, b1, nullptr, inter, 1024, 4096);
    // 7) out = x1 + inter @ W2 + b2 -> fp32 d_out (in place, disjoint tiles)
    gemm_mfma<false, true, false, true><<<dim3(8, 160), 256, 0, stream>>>(
        inter, W2T, b2, out, out, 4096, 1024);
}

// Round 4
// 1138.674 us; speedup vs baseline: 1.2891x; 1.2891x over previous
//
#include <hip/hip_runtime.h>

// Transformer block: B=64, T=320, E=1024, H=16, HS=64
// Round 3: MFMA attention (swapped QK^T, XOR-swizzled LDS, P via LDS).
// GEMMs unchanged from round 2 (validated: absmax 0.031).

#define B_ 64
#define T_ 320
#define E_ 1024
#define H_ 16
#define HS_ 64
#define NTOK (B_ * T_)   // 20480

typedef __attribute__((ext_vector_type(8))) __bf16 bf16x8;
typedef __attribute__((ext_vector_type(4))) float f32x4;

__device__ __forceinline__ unsigned short f2bf(float f) {
    unsigned u = __builtin_bit_cast(unsigned, f);
    u += 0x7fffu + ((u >> 16) & 1u);          // round-to-nearest-even
    return (unsigned short)(u >> 16);
}
__device__ __forceinline__ float bf2f(unsigned short b) {
    return __builtin_bit_cast(float, (unsigned)b << 16);
}

// ------------------------------------------------------------ LayerNorm -> bf16
__global__ __launch_bounds__(256) void ln_kernel(const float* __restrict__ x,
                                                 const float* __restrict__ w,
                                                 const float* __restrict__ b,
                                                 unsigned short* __restrict__ y) {
    int row = blockIdx.x;
    int t = threadIdx.x;
    const float4* xr = (const float4*)(x + (size_t)row * E_);
    float4 v = xr[t];
    float s = v.x + v.y + v.z + v.w;
    float s2 = v.x * v.x + v.y * v.y + v.z * v.z + v.w * v.w;
#pragma unroll
    for (int o = 1; o < 64; o <<= 1) {
        s += __shfl_xor(s, o);
        s2 += __shfl_xor(s2, o);
    }
    __shared__ float rs[4], rs2[4];
    int wv = t >> 6;
    if ((t & 63) == 0) { rs[wv] = s; rs2[wv] = s2; }
    __syncthreads();
    s = rs[0] + rs[1] + rs[2] + rs[3];
    s2 = rs2[0] + rs2[1] + rs2[2] + rs2[3];
    float mu = s * (1.0f / E_);
    float var = s2 * (1.0f / E_) - mu * mu;
    float inv = rsqrtf(var + 1e-5f);
    float4 w4 = ((const float4*)w)[t];
    float4 b4 = ((const float4*)b)[t];
    ushort4 o4;
    o4.x = f2bf((v.x - mu) * inv * w4.x + b4.x);
    o4.y = f2bf((v.y - mu) * inv * w4.y + b4.y);
    o4.z = f2bf((v.z - mu) * inv * w4.z + b4.z);
    o4.w = f2bf((v.w - mu) * inv * w4.w + b4.w);
    *(ushort4*)(y + (size_t)row * E_ + 4 * t) = o4;
}

// ------------------------------------------------- transpose-cast fp32->bf16
__global__ __launch_bounds__(256) void tcast_kernel(const float* __restrict__ src,
                                                    unsigned short* __restrict__ dst,
                                                    int K, int N, long sStride, long dStride) {
    src += (size_t)blockIdx.z * sStride;
    dst += (size_t)blockIdx.z * dStride;
    __shared__ float tile[64][65];
    int k0 = blockIdx.y * 64, n0 = blockIdx.x * 64;
    int tx = threadIdx.x & 63, ty = threadIdx.x >> 6;
#pragma unroll
    for (int r = ty; r < 64; r += 4)
        tile[r][tx] = src[(size_t)(k0 + r) * N + n0 + tx];
    __syncthreads();
#pragma unroll
    for (int r = ty; r < 64; r += 4)
        dst[(size_t)(n0 + r) * K + k0 + tx] = f2bf(tile[tx][r]);
}

// ------------------------------------------------------------- MFMA GEMM
// (unchanged, validated round 2)
template <bool BF16OUT, bool BIAS, bool RELU, bool RESID>
__global__ __launch_bounds__(256)
void gemm_mfma(const unsigned short* __restrict__ A,   // [M][K] bf16
               const unsigned short* __restrict__ Bt,  // [N][K] bf16
               const float* __restrict__ bias,         // [N] fp32
               const float* __restrict__ resid,        // [M][N] fp32
               void* __restrict__ Cout, int K, int N) {
    __shared__ uint4 A4[128 * 4];
    __shared__ uint4 B4[128 * 4];
    const int tid = threadIdx.x;
    const int lane = tid & 63;
    const int wave = tid >> 6;
    const int wr = wave >> 1, wc = wave & 1;
    const int m0 = blockIdx.y * 128;
    const int n0 = blockIdx.x * 128;
    const int r16 = lane & 15;
    const int s = lane >> 4;
    const int sw = s ^ ((r16 >> 1) & 3);

    const int ar0 = tid >> 2, as0 = tid & 3;
    const int asw = as0 ^ ((ar0 >> 1) & 3);
    const unsigned short* Ag = A + (size_t)(m0 + ar0) * K + as0 * 8;
    const unsigned short* Bg = Bt + (size_t)(n0 + ar0) * K + as0 * 8;
    const size_t rowSkip = (size_t)64 * K;

    f32x4 acc[4][4];
#pragma unroll
    for (int i = 0; i < 4; i++)
#pragma unroll
        for (int j = 0; j < 4; j++) acc[i][j] = (f32x4){0.f, 0.f, 0.f, 0.f};

    const bf16x8* Ab = (const bf16x8*)A4;
    const bf16x8* Bb = (const bf16x8*)B4;

    for (int k0 = 0; k0 < K; k0 += 32) {
        uint4 a0 = *(const uint4*)(Ag + k0);
        uint4 a1 = *(const uint4*)(Ag + rowSkip + k0);
        uint4 b0 = *(const uint4*)(Bg + k0);
        uint4 b1 = *(const uint4*)(Bg + rowSkip + k0);
        __syncthreads();
        A4[(ar0 << 2) + asw] = a0;
        A4[((ar0 + 64) << 2) + asw] = a1;
        B4[(ar0 << 2) + asw] = b0;
        B4[((ar0 + 64) << 2) + asw] = b1;
        __syncthreads();
        bf16x8 af[4], bf[4];
#pragma unroll
        for (int i = 0; i < 4; i++) {
            af[i] = Ab[(((wr << 6) + (i << 4) + r16) << 2) + sw];
            bf[i] = Bb[(((wc << 6) + (i << 4) + r16) << 2) + sw];
        }
#pragma unroll
        for (int i = 0; i < 4; i++)
#pragma unroll
            for (int j = 0; j < 4; j++)
                acc[i][j] = __builtin_amdgcn_mfma_f32_16x16x32_bf16(af[i], bf[j], acc[i][j], 0, 0, 0);
    }

    const int crow0 = m0 + wr * 64;
    const int ccol0 = n0 + wc * 64;
#pragma unroll
    for (int j = 0; j < 4; j++) {
        int gcol = ccol0 + j * 16 + r16;
        float bv = BIAS ? bias[gcol] : 0.f;
#pragma unroll
        for (int i = 0; i < 4; i++) {
            int growb = crow0 + i * 16 + s * 4;
#pragma unroll
            for (int r = 0; r < 4; r++) {
                float vo = acc[i][j][r] + bv;
                if (RELU) vo = fmaxf(vo, 0.f);
                int grow = growb + r;
                if (RESID) vo += resid[(size_t)grow * N + gcol];
                if (BF16OUT)
                    ((unsigned short*)Cout)[(size_t)grow * N + gcol] = f2bf(vo);
                else
                    ((float*)Cout)[(size_t)grow * N + gcol] = vo;
            }
        }
    }
}

// ------------------------------------------------------------- MFMA Flash attn
// grid (5, B*H), 256 threads = 4 waves. Wave w owns q-rows [w*16, w*16+16).
// Swapped QK^T: S^T = mfma(K, Q) -> lane's q-row = lane&15 -> per-lane scalar
// m,l; softmax reduce = 2 shuffles. P -> per-wave LDS -> PV: O^T = mfma(Vt, P).
// All LDS tiles XOR-swizzled at 16B-slot granularity (slot ^= row&7).
__global__ __launch_bounds__(256) void attn_mfma(const unsigned short* __restrict__ qkv,
                                                 unsigned short* __restrict__ attn) {
    const int it = blockIdx.x;
    const int bh = blockIdx.y;
    const int b = bh >> 4, head = bh & 15;
    __shared__ uint4 KsV[512];          // K tile  [kv=64][d=64] bf16, swizzled
    __shared__ uint4 VtV[512];          // V^T tile [d=64][kv=64] bf16, swizzled
    __shared__ uint4 PsV[4][128];       // per-wave P [q=16][kv=64] bf16, swizzled
    unsigned short* Ks = (unsigned short*)KsV;
    unsigned short* Vt = (unsigned short*)VtV;

    const int tid = threadIdx.x;
    const int lane = tid & 63;
    const int w = tid >> 6;
    const int r16 = lane & 15;          // = this lane's q-row (local to wave)
    const int s = lane >> 4;
    unsigned short* P = (unsigned short*)PsV[w];

    const int qg = it * 64 + w * 16 + r16;            // global q position
    const size_t qrow = (size_t)(b * T_ + qg) * 3072;

    // Q fragments in registers: lane holds Q[q=r16][d = c*32 + 8s .. +7]
    bf16x8 qf0 = *(const bf16x8*)(qkv + qrow + head * 64 + 0 * 32 + s * 8);
    bf16x8 qf1 = *(const bf16x8*)(qkv + qrow + head * 64 + 1 * 32 + s * 8);

    f32x4 accO[4];
#pragma unroll
    for (int i = 0; i < 4; i++) accO[i] = (f32x4){0.f, 0.f, 0.f, 0.f};
    float m = -1e30f, l = 0.f;

    for (int j = 0; j <= it; j++) {
        __syncthreads();                // prev-iter Ks/Vt readers done
        // ---- stage K [kv][d] and V^T [d][kv], both swizzled ----
#pragma unroll
        for (int half = 0; half < 2; half++) {
            int cid = tid + half * 256;               // 512 chunks of 16B
            int row = cid >> 3, sl = cid & 7;         // row=kv, sl=d-slot
            size_t tok = (size_t)(b * T_ + j * 64 + row) * 3072 + head * 64 + sl * 8;
            uint4 kc = *(const uint4*)(qkv + tok + 1024);
            uint4 vc = *(const uint4*)(qkv + tok + 2048);
            *(uint4*)(Ks + row * 64 + ((sl ^ (row & 7)) * 8)) = kc;
            union { uint4 u; unsigned short h[8]; } vv; vv.u = vc;
#pragma unroll
            for (int e = 0; e < 8; e++) {
                int d = sl * 8 + e;
                Vt[d * 64 + (((row >> 3) ^ (d & 7)) * 8) + (row & 7)] = vv.h[e];
            }
        }
        __syncthreads();

        // ---- S^T = K @ Q^T : D[kv=16i+4s+r][q=r16] ----
        f32x4 accS[4];
#pragma unroll
        for (int i = 0; i < 4; i++) accS[i] = (f32x4){0.f, 0.f, 0.f, 0.f};
#pragma unroll
        for (int c = 0; c < 2; c++) {
            bf16x8 qc = c ? qf1 : qf0;
#pragma unroll
            for (int i = 0; i < 4; i++) {
                int kvr = i * 16 + r16;
                bf16x8 kf = *(const bf16x8*)(Ks + kvr * 64 + (((c * 4 + s) ^ (kvr & 7)) * 8));
                accS[i] = __builtin_amdgcn_mfma_f32_16x16x32_bf16(kf, qc, accS[i], 0, 0, 0);
            }
        }

        // ---- online softmax (per-lane: one q-row) ----
        float sv[16];
        float smax = -1e30f;
#pragma unroll
        for (int i = 0; i < 4; i++)
#pragma unroll
            for (int r = 0; r < 4; r++) {
                float vsc = accS[i][r] * 0.03125f;        // * E^-0.5
                int kvg = j * 64 + i * 16 + 4 * s + r;
                if (kvg > qg) vsc = -1e30f;               // causal (only fires j==it)
                sv[i * 4 + r] = vsc;
                smax = fmaxf(smax, vsc);
            }
        smax = fmaxf(smax, __shfl_xor(smax, 16));
        smax = fmaxf(smax, __shfl_xor(smax, 32));
        float mn = fmaxf(m, smax);
        float al = __expf(m - mn);
        float ps = 0.f;
        unsigned short pb[16];
#pragma unroll
        for (int idx = 0; idx < 16; idx++) {
            float p = __expf(sv[idx] - mn);
            ps += p;
            pb[idx] = f2bf(p);
        }
        ps += __shfl_xor(ps, 16);
        ps += __shfl_xor(ps, 32);
        l = l * al + ps;
        m = mn;
#pragma unroll
        for (int i = 0; i < 4; i++)
#pragma unroll
            for (int r = 0; r < 4; r++) accO[i][r] *= al;

        // ---- P -> per-wave LDS [q=r16][kv], swizzled ----
#pragma unroll
        for (int i = 0; i < 4; i++)
#pragma unroll
            for (int r = 0; r < 4; r++) {
                int kv = i * 16 + 4 * s + r;
                P[r16 * 64 + (((kv >> 3) ^ (r16 & 7)) * 8) + (kv & 7)] = pb[i * 4 + r];
            }
        asm volatile("s_waitcnt lgkmcnt(0)" ::: "memory");   // wave-local P ready

        // ---- O^T += V^T @ P^T : D[d=16i+4s+r][q=r16] ----
#pragma unroll
        for (int c = 0; c < 2; c++) {
            bf16x8 pf = *(const bf16x8*)(P + r16 * 64 + (((c * 4 + s) ^ (r16 & 7)) * 8));
#pragma unroll
            for (int i = 0; i < 4; i++) {
                int d = i * 16 + r16;
                bf16x8 vf = *(const bf16x8*)(Vt + d * 64 + (((c * 4 + s) ^ (d & 7)) * 8));
                accO[i] = __builtin_amdgcn_mfma_f32_16x16x32_bf16(vf, pf, accO[i], 0, 0, 0);
            }
        }
    }

    // ---- epilogue: O^T regs -> per-wave LDS [q][d] -> coalesced global ----
    float inv = 1.0f / l;
#pragma unroll
    for (int i = 0; i < 4; i++)
#pragma unroll
        for (int r = 0; r < 4; r++) {
            int d = i * 16 + 4 * s + r;
            P[r16 * 64 + (((d >> 3) ^ (r16 & 7)) * 8) + (d & 7)] = f2bf(accO[i][r] * inv);
        }
    asm volatile("s_waitcnt lgkmcnt(0)" ::: "memory");
#pragma unroll
    for (int half = 0; half < 2; half++) {
        int cid = lane + half * 64;                   // 128 chunks of 16B
        int row = cid >> 3, sl = cid & 7;             // row=q-local, sl=d-slot
        uint4 o = *(const uint4*)(P + row * 64 + ((sl ^ (row & 7)) * 8));
        *(uint4*)(attn + (size_t)(b * T_ + it * 64 + w * 16 + row) * E_ + head * 64 + sl * 8) = o;
    }
}

// ---------------------------------------------------------------- launch
extern "C" void kernel_launch(void* const* d_in, const int* in_sizes, int n_in,
                              void* d_out, int out_size, void* d_ws, size_t ws_size,
                              hipStream_t stream) {
    const float* x    = (const float*)d_in[0];
    const float* Wq   = (const float*)d_in[1];
    const float* Wk   = (const float*)d_in[2];
    const float* Wv   = (const float*)d_in[3];
    const float* Wo   = (const float*)d_in[4];
    const float* bo   = (const float*)d_in[5];
    const float* W1   = (const float*)d_in[6];
    const float* b1   = (const float*)d_in[7];
    const float* W2   = (const float*)d_in[8];
    const float* b2   = (const float*)d_in[9];
    const float* ln1w = (const float*)d_in[10];
    const float* ln1b = (const float*)d_in[11];
    const float* ln2w = (const float*)d_in[12];
    const float* ln2b = (const float*)d_in[13];
    float* out = (float*)d_out;

    unsigned short* ws = (unsigned short*)d_ws;
    unsigned short* qkvWt = ws;                        //  [3072][1024]
    unsigned short* WoT   = qkvWt + 3072 * 1024;       //  [1024][1024]
    unsigned short* W1T   = WoT + 1024 * 1024;         //  [4096][1024]
    unsigned short* W2T   = W1T + 4096 * 1024;         //  [1024][4096]
    unsigned short* hbuf  = W2T + 1024 * 4096;         //  [20480][1024]
    unsigned short* qkv   = hbuf + (size_t)NTOK * E_;  //  [20480][3072]
    unsigned short* abuf  = qkv + (size_t)NTOK * 3 * E_; // [20480][1024]
    unsigned short* inter = qkv;                       //  [20480][4096] overlays qkv+abuf

    tcast_kernel<<<dim3(1, 16, 16), 256, 0, stream>>>(Wq, qkvWt, E_, HS_,
                                                      (long)E_ * HS_, (long)HS_ * E_);
    tcast_kernel<<<dim3(1, 16, 16), 256, 0, stream>>>(Wk, qkvWt + 1024 * 1024, E_, HS_,
                                                      (long)E_ * HS_, (long)HS_ * E_);
    tcast_kernel<<<dim3(1, 16, 16), 256, 0, stream>>>(Wv, qkvWt + 2048 * 1024, E_, HS_,
                                                      (long)E_ * HS_, (long)HS_ * E_);
    tcast_kernel<<<dim3(16, 16, 1), 256, 0, stream>>>(Wo, WoT, E_, E_, 0, 0);
    tcast_kernel<<<dim3(64, 16, 1), 256, 0, stream>>>(W1, W1T, E_, 4 * E_, 0, 0);
    tcast_kernel<<<dim3(16, 64, 1), 256, 0, stream>>>(W2, W2T, 4 * E_, E_, 0, 0);

    // 1) h = LN1(x) -> bf16
    ln_kernel<<<NTOK, 256, 0, stream>>>(x, ln1w, ln1b, hbuf);
    // 2) qkv = h @ [Wq|Wk|Wv]
    gemm_mfma<true, false, false, false><<<dim3(24, 160), 256, 0, stream>>>(
        hbuf, qkvWt, nullptr, nullptr, qkv, 1024, 3072);
    // 3) attention (MFMA) -> bf16 (B,T,E)
    attn_mfma<<<dim3(T_ / 64, B_ * H_), 256, 0, stream>>>(qkv, abuf);
    // 4) x1 = x + attn @ Wo + bo -> fp32 d_out
    gemm_mfma<false, true, false, true><<<dim3(8, 160), 256, 0, stream>>>(
        abuf, WoT, bo, x, out, 1024, 1024);
    // 5) h2 = LN2(x1) -> bf16
    ln_kernel<<<NTOK, 256, 0, stream>>>(out, ln2w, ln2b, hbuf);
    // 6) inter = relu(h2 @ W1 + b1) -> bf16
    gemm_mfma<true, true, true, false><<<dim3(32, 160), 256, 0, stream>>>(
        hbuf, W1T, b1, nullptr, inter, 1024, 4096);
    // 7) out = x1 + inter @ W2 + b2 -> fp32 d_out
    gemm_mfma<false, true, false, true><<<dim3(8, 160), 256, 0, stream>>>(
        inter, W2T, b2, out, out, 4096, 1024);
}